// Round 4
// baseline (866.482 us; speedup 1.0000x reference)
//
#include <hip/hip_runtime.h>

#define NN 100000
#define EE 6400000
#define PP 12
#define FF 32

// fast-path bucketing: bucket = 128 consecutive node ids
#define VV   128          // nodes per bucket
#define BB   782          // ceil(NN/VV)
#define CAP  9216         // per-bucket edge capacity; mean 8192, sigma~90 -> >10 sigma
#define K1B  400          // bucket_k blocks
#define CHK  16000        // edges per bucket_k block (K1B*CHK == EE)

// ---------------- precompute: probs + collapsed GRU tables ----------------
// tabs layout: [0..11] probs, [16..47] az, [48..79] cz, [80..111] ah, [112..143] ch
__global__ void precompute_k(const float* __restrict__ att,
                             const float* __restrict__ wc_z, const float* __restrict__ bc_z,
                             const float* __restrict__ wc_h, const float* __restrict__ bc_h,
                             const float* __restrict__ wl_z, const float* __restrict__ bl_z,
                             const float* __restrict__ wl_h, const float* __restrict__ bl_h,
                             float* __restrict__ tabs) {
    int j = threadIdx.x;
    if (j < FF) {
        float az = 0.f, cz = 0.f, ah = 0.f, ch = 0.f;
        for (int f = 0; f < FF; ++f) {
            float wz = wl_z[f * FF + j];
            float wh = wl_h[f * FF + j];
            az += wc_z[f] * wz;
            cz += bc_z[f] * wz;
            ah += wc_h[f] * wh;
            ch += bc_h[f] * wh;
        }
        tabs[16 + j]          = az;
        tabs[16 + FF + j]     = cz + bl_z[j];
        tabs[16 + 2 * FF + j] = ah;
        tabs[16 + 3 * FF + j] = ch + bl_h[j];
    } else if (j == FF) {
        float a[PP];
        float m = -1e30f;
        for (int p = 0; p < PP; ++p) { a[p] = att[p]; m = fmaxf(m, a[p]); }
        float s = 0.f;
        for (int p = 0; p < PP; ++p) { a[p] = __expf(a[p] - m); s += a[p]; }
        for (int p = 0; p < PP; ++p) tabs[p] = a[p] / s;
    }
}

// ---------------- K1: bucket-scatter with block-aggregated claims ----------------
// recs[b*CAP + k] = uint2{ (local<<17)|src , bits(w) }
__global__ __launch_bounds__(256) void bucket_k(const int* __restrict__ src,
                                                const int* __restrict__ dst,
                                                const float* __restrict__ ew,
                                                int* __restrict__ bucket_cnt,
                                                uint2* __restrict__ recs) {
    __shared__ int hist[BB];
    __shared__ int offs[BB];
    int tid = threadIdx.x;
    int beg = blockIdx.x * CHK;
    int end = beg + CHK;

    for (int b = tid; b < BB; b += 256) hist[b] = 0;
    __syncthreads();

    // phase A: histogram of dst buckets for this chunk
    for (int e = beg + tid; e < end; e += 256)
        atomicAdd(&hist[dst[e] >> 7], 1);
    __syncthreads();

    // phase B: one device atomic per (block, bucket) claims a contiguous range
    for (int b = tid; b < BB; b += 256) {
        int h = hist[b];
        offs[b] = h ? atomicAdd(&bucket_cnt[b], h) : 0;
    }
    __syncthreads();

    // phase C: place records at LDS-claimed positions
    for (int e = beg + tid; e < end; e += 256) {
        int d = dst[e];
        int bin   = d >> 7;
        int local = d & (VV - 1);
        int o = atomicAdd(&offs[bin], 1);
        if (o < CAP) {
            uint2 r;
            r.x = ((unsigned)local << 17) | (unsigned)src[e];
            r.y = __float_as_uint(ew[e]);
            recs[(size_t)bin * CAP + o] = r;
        }
    }
}

// ---------------- K2: per-bucket degree -> dinv (LDS atomics only) ----------------
__global__ __launch_bounds__(256) void bdeg_k(const int* __restrict__ bucket_cnt,
                                              const uint2* __restrict__ recs,
                                              float* __restrict__ dinv) {
    __shared__ float deg[VV];
    int b = blockIdx.x;
    int tid = threadIdx.x;
    if (tid < VV) deg[tid] = 0.f;
    __syncthreads();
    int n = min(bucket_cnt[b], CAP);
    const uint2* r = recs + (size_t)b * CAP;
    for (int k = tid; k < n; k += 256) {
        uint2 v = r[k];
        atomicAdd(&deg[v.x >> 17], __uint_as_float(v.y));
    }
    __syncthreads();
    int node = b * VV + tid;
    if (tid < VV && node < NN)
        dinv[node] = rsqrtf(deg[tid] + 1.0f);
}

// ---------------- K3: per-bucket aggregate + fused GRU/attention/output ----------------
__global__ __launch_bounds__(256) void bagg_k(const int* __restrict__ bucket_cnt,
                                              const uint2* __restrict__ recs,
                                              const float* __restrict__ dinv,
                                              const float* __restrict__ x,
                                              const float* __restrict__ tabs,
                                              const float* __restrict__ w_out,
                                              const float* __restrict__ b_out,
                                              float* __restrict__ out) {
    __shared__ float agg[VV * PP];   // 6 KB
    int b = blockIdx.x;
    int tid = threadIdx.x;
    for (int k = tid; k < VV * PP; k += 256) agg[k] = 0.f;
    __syncthreads();

    int n = min(bucket_cnt[b], CAP);
    const uint2* r = recs + (size_t)b * CAP;
    for (int k = tid; k < n; k += 256) {
        uint2 v = r[k];
        int   s     = (int)(v.x & 0x1FFFFu);
        int   local = (int)(v.x >> 17);
        float c = __uint_as_float(v.y) * dinv[s];
        const float4* xs = (const float4*)(x + (size_t)s * PP);
        float4 v0 = xs[0], v1 = xs[1], v2 = xs[2];
        float* a = agg + local * PP;
        atomicAdd(&a[0],  c * v0.x);
        atomicAdd(&a[1],  c * v0.y);
        atomicAdd(&a[2],  c * v0.z);
        atomicAdd(&a[3],  c * v0.w);
        atomicAdd(&a[4],  c * v1.x);
        atomicAdd(&a[5],  c * v1.y);
        atomicAdd(&a[6],  c * v1.z);
        atomicAdd(&a[7],  c * v1.w);
        atomicAdd(&a[8],  c * v2.x);
        atomicAdd(&a[9],  c * v2.y);
        atomicAdd(&a[10], c * v2.z);
        atomicAdd(&a[11], c * v2.w);
    }
    __syncthreads();

    // fused head: 8 groups of 32 lanes; group handles nodes local = g, g+8, ...
    int g = tid >> 5;
    int j = tid & 31;
    float azj = tabs[16 + j];
    float czj = tabs[16 + FF + j];
    float ahj = tabs[16 + 2 * FF + j];
    float chj = tabs[16 + 3 * FF + j];
    float wj  = w_out[j];
    float bo  = b_out[0];

    for (int local = g; local < VV; local += 8) {
        int node = b * VV + local;
        if (node >= NN) break;
        float dv  = dinv[node];
        float dv2 = dv * dv;
        const float* an = agg + local * PP;
        const float* xn = x + (size_t)node * PP;
        float accum = 0.f;
        #pragma unroll
        for (int p = 0; p < PP; ++p) {
            float sp = dv * an[p] + dv2 * xn[p];
            float pr = tabs[p];
            float uz = sp * azj + czj;
            float uh = sp * ahj + chj;
            float one_minus_z = 1.0f / (1.0f + __expf(uz));   // sigma(-uz)
            float e2h = __expf(2.0f * uh);
            float th  = 1.0f - 2.0f / (e2h + 1.0f);           // tanh(uh)
            accum += pr * one_minus_z * th;
        }
        float h = fmaxf(accum, 0.f) * wj;
        #pragma unroll
        for (int off = 16; off > 0; off >>= 1)
            h += __shfl_xor(h, off, 32);
        if (j == 0) out[node] = h + bo;
    }
}

// ---------------- fallback path (round-2 proven kernels) ----------------
__global__ __launch_bounds__(256) void deg_k(const int* __restrict__ dst,
                                             const float* __restrict__ ew,
                                             float* __restrict__ deg) {
    int stride = gridDim.x * blockDim.x;
    for (int e = blockIdx.x * blockDim.x + threadIdx.x; e < EE; e += stride)
        atomicAdd(&deg[dst[e]], ew[e]);
}

__global__ __launch_bounds__(256) void dinv_self_k(const float* __restrict__ x,
                                                   float* __restrict__ deg,
                                                   float* __restrict__ agg) {
    int i = blockIdx.x * blockDim.x + threadIdx.x;
    if (i >= NN) return;
    float d  = deg[i] + 1.0f;
    float dv = rsqrtf(d);
    deg[i]   = dv;
    float dv2 = dv * dv;
    const float4* xr = (const float4*)(x + (size_t)i * PP);
    float4* ar = (float4*)(agg + (size_t)i * PP);
    #pragma unroll
    for (int q = 0; q < 3; ++q) {
        float4 v = xr[q];
        v.x *= dv2; v.y *= dv2; v.z *= dv2; v.w *= dv2;
        ar[q] = v;
    }
}

__global__ __launch_bounds__(256) void agg_k(const int* __restrict__ src,
                                             const int* __restrict__ dst,
                                             const float* __restrict__ ew,
                                             const float* __restrict__ x,
                                             const float* __restrict__ dinv,
                                             float* __restrict__ agg) {
    int stride = gridDim.x * blockDim.x;
    for (int e = blockIdx.x * blockDim.x + threadIdx.x; e < EE; e += stride) {
        int s = src[e];
        int d = dst[e];
        float nw = dinv[s] * ew[e] * dinv[d];
        const float4* xs = (const float4*)(x + (size_t)s * PP);
        float* ad = agg + (size_t)d * PP;
        float4 v0 = xs[0], v1 = xs[1], v2 = xs[2];
        atomicAdd(&ad[0],  nw * v0.x);
        atomicAdd(&ad[1],  nw * v0.y);
        atomicAdd(&ad[2],  nw * v0.z);
        atomicAdd(&ad[3],  nw * v0.w);
        atomicAdd(&ad[4],  nw * v1.x);
        atomicAdd(&ad[5],  nw * v1.y);
        atomicAdd(&ad[6],  nw * v1.z);
        atomicAdd(&ad[7],  nw * v1.w);
        atomicAdd(&ad[8],  nw * v2.x);
        atomicAdd(&ad[9],  nw * v2.y);
        atomicAdd(&ad[10], nw * v2.z);
        atomicAdd(&ad[11], nw * v2.w);
    }
}

__global__ __launch_bounds__(256) void node_k(const float* __restrict__ agg,
                                              const float* __restrict__ tabs,
                                              const float* __restrict__ w_out,
                                              const float* __restrict__ b_out,
                                              float* __restrict__ out) {
    int t = blockIdx.x * blockDim.x + threadIdx.x;
    int i = t >> 5;
    int j = t & 31;
    if (i >= NN) return;
    float azj = tabs[16 + j];
    float czj = tabs[16 + FF + j];
    float ahj = tabs[16 + 2 * FF + j];
    float chj = tabs[16 + 3 * FF + j];
    float acc = 0.f;
    #pragma unroll
    for (int p = 0; p < PP; ++p) {
        float s  = agg[i * PP + p];
        float pr = tabs[p];
        float uz = s * azj + czj;
        float uh = s * ahj + chj;
        float one_minus_z = 1.0f / (1.0f + __expf(uz));
        float e2h = __expf(2.0f * uh);
        float th  = 1.0f - 2.0f / (e2h + 1.0f);
        acc += pr * one_minus_z * th;
    }
    float h = fmaxf(acc, 0.f) * w_out[j];
    #pragma unroll
    for (int off = 16; off > 0; off >>= 1)
        h += __shfl_xor(h, off, 32);
    if (j == 0) out[i] = h + b_out[0];
}

extern "C" void kernel_launch(void* const* d_in, const int* in_sizes, int n_in,
                              void* d_out, int out_size, void* d_ws, size_t ws_size,
                              hipStream_t stream) {
    const float* x    = (const float*)d_in[0];
    const int*   ei   = (const int*)d_in[1];
    const float* ew   = (const float*)d_in[2];
    const float* att  = (const float*)d_in[3];
    const float* wc_z = (const float*)d_in[4];
    const float* bc_z = (const float*)d_in[5];
    const float* wc_h = (const float*)d_in[8];
    const float* bc_h = (const float*)d_in[9];
    const float* wl_z = (const float*)d_in[10];
    const float* bl_z = (const float*)d_in[11];
    const float* wl_h = (const float*)d_in[14];
    const float* bl_h = (const float*)d_in[15];
    const float* wout = (const float*)d_in[16];
    const float* bout = (const float*)d_in[17];
    float* out = (float*)d_out;

    const int* src = ei;
    const int* dst = ei + EE;

    size_t recs_bytes = (size_t)BB * CAP * sizeof(uint2);   // ~57.7 MB
    size_t need = recs_bytes + BB * 4 + (size_t)NN * 4 + 1024;

    if (ws_size >= need) {
        uint2* recs       = (uint2*)d_ws;
        int*   bucket_cnt = (int*)((char*)d_ws + recs_bytes);
        float* dinv       = (float*)(bucket_cnt + BB);
        float* tabs       = dinv + NN;

        hipMemsetAsync(bucket_cnt, 0, BB * sizeof(int), stream);
        precompute_k<<<1, 64, 0, stream>>>(att, wc_z, bc_z, wc_h, bc_h, wl_z, bl_z, wl_h, bl_h, tabs);
        bucket_k<<<K1B, 256, 0, stream>>>(src, dst, ew, bucket_cnt, recs);
        bdeg_k<<<BB, 256, 0, stream>>>(bucket_cnt, recs, dinv);
        bagg_k<<<BB, 256, 0, stream>>>(bucket_cnt, recs, dinv, x, tabs, wout, bout, out);
    } else {
        float* deg  = (float*)d_ws;
        float* agg  = deg + NN;
        float* tabs = agg + (size_t)NN * PP;

        hipMemsetAsync(deg, 0, NN * sizeof(float), stream);
        precompute_k<<<1, 64, 0, stream>>>(att, wc_z, bc_z, wc_h, bc_h, wl_z, bl_z, wl_h, bl_h, tabs);
        deg_k<<<4096, 256, 0, stream>>>(dst, ew, deg);
        dinv_self_k<<<(NN + 255) / 256, 256, 0, stream>>>(x, deg, agg);
        agg_k<<<8192, 256, 0, stream>>>(src, dst, ew, x, deg, agg);
        node_k<<<NN * 32 / 256, 256, 0, stream>>>(agg, tabs, wout, bout, out);
    }
}

// Round 5
// 454.210 us; speedup vs baseline: 1.9077x; 1.9077x over previous
//
#include <hip/hip_runtime.h>

#define NN 100000
#define EE 6400000
#define PP 12
#define FF 32

// two-level sort: bucket = 256 consecutive node ids
#define VV   256            // nodes per bucket
#define BB   391            // ceil(NN/VV)
#define CAP  17152          // per-bucket capacity; mean 16384, sigma~128 -> +6 sigma
#define K1B  400            // bucket_k blocks
#define CHK  16000          // edges per bucket_k block (K1B*CHK == EE)

// ---------------- precompute: probs + collapsed GRU tables ----------------
// tabs layout: [0..11] probs, [16..47] az, [48..79] cz, [80..111] ah, [112..143] ch
__global__ void precompute_k(const float* __restrict__ att,
                             const float* __restrict__ wc_z, const float* __restrict__ bc_z,
                             const float* __restrict__ wc_h, const float* __restrict__ bc_h,
                             const float* __restrict__ wl_z, const float* __restrict__ bl_z,
                             const float* __restrict__ wl_h, const float* __restrict__ bl_h,
                             float* __restrict__ tabs) {
    int j = threadIdx.x;
    if (j < FF) {
        float az = 0.f, cz = 0.f, ah = 0.f, ch = 0.f;
        for (int f = 0; f < FF; ++f) {
            float wz = wl_z[f * FF + j];
            float wh = wl_h[f * FF + j];
            az += wc_z[f] * wz;
            cz += bc_z[f] * wz;
            ah += wc_h[f] * wh;
            ch += bc_h[f] * wh;
        }
        tabs[16 + j]          = az;
        tabs[16 + FF + j]     = cz + bl_z[j];
        tabs[16 + 2 * FF + j] = ah;
        tabs[16 + 3 * FF + j] = ch + bl_h[j];
    } else if (j == FF) {
        float a[PP];
        float m = -1e30f;
        for (int p = 0; p < PP; ++p) { a[p] = att[p]; m = fmaxf(m, a[p]); }
        float s = 0.f;
        for (int p = 0; p < PP; ++p) { a[p] = __expf(a[p] - m); s += a[p]; }
        for (int p = 0; p < PP; ++p) tabs[p] = a[p] / s;
    }
}

// ---------------- K1: bucket-scatter with block-aggregated claims ----------------
// recs[b*CAP + k] = uint2{ (local<<17)|src , bits(w) }   (src < 2^17, local < 256)
__global__ __launch_bounds__(256) void bucket_k(const int* __restrict__ src,
                                                const int* __restrict__ dst,
                                                const float* __restrict__ ew,
                                                int* __restrict__ bucket_cnt,
                                                uint2* __restrict__ recs) {
    __shared__ int hist[BB];
    __shared__ int offs[BB];
    int tid = threadIdx.x;
    int beg = blockIdx.x * CHK;
    int end = beg + CHK;

    for (int b = tid; b < BB; b += 256) hist[b] = 0;
    __syncthreads();

    for (int e = beg + tid; e < end; e += 256)
        atomicAdd(&hist[dst[e] >> 8], 1);
    __syncthreads();

    // one device atomic per (block, bucket)
    for (int b = tid; b < BB; b += 256) {
        int h = hist[b];
        offs[b] = h ? atomicAdd(&bucket_cnt[b], h) : 0;
    }
    __syncthreads();

    for (int e = beg + tid; e < end; e += 256) {
        int d = dst[e];
        int bin   = d >> 8;
        int local = d & (VV - 1);
        int o = atomicAdd(&offs[bin], 1);
        if (o < CAP) {
            uint2 r;
            r.x = ((unsigned)local << 17) | (unsigned)src[e];
            r.y = __float_as_uint(ew[e]);
            recs[(size_t)bin * CAP + o] = r;
        }
    }
}

// ---------------- K2: per-bucket counting sort by node + fused degree ----------------
__global__ __launch_bounds__(256) void sort_k(const int* __restrict__ bucket_cnt,
                                              const uint2* __restrict__ recs,
                                              uint2* __restrict__ srt,
                                              float* __restrict__ dinv,
                                              int* __restrict__ starts,
                                              int* __restrict__ cnts) {
    __shared__ int   h[VV];
    __shared__ float wsum[VV];
    __shared__ int   offs[VV];
    int b = blockIdx.x;
    int tid = threadIdx.x;

    h[tid] = 0;
    wsum[tid] = 0.f;
    __syncthreads();

    int n = min(bucket_cnt[b], CAP);
    const uint2* r = recs + (size_t)b * CAP;

    // histogram + weight sum (stride-1 LDS, ~2-way conflicts = free)
    for (int k = tid; k < n; k += 256) {
        uint2 v = r[k];
        int local = (int)(v.x >> 17);
        atomicAdd(&h[local], 1);
        atomicAdd(&wsum[local], __uint_as_float(v.y));
    }
    __syncthreads();

    int own = h[tid];
    // Hillis-Steele inclusive scan over h[256]
    #pragma unroll
    for (int off = 1; off < VV; off <<= 1) {
        int t = (tid >= off) ? h[tid - off] : 0;
        __syncthreads();
        h[tid] += t;
        __syncthreads();
    }
    int pre = h[tid] - own;
    offs[tid] = pre;

    int node = b * VV + tid;
    if (node < NN) {
        dinv[node]   = rsqrtf(wsum[tid] + 1.0f);
        starts[node] = b * CAP + pre;
        cnts[node]   = own;
    }
    __syncthreads();

    // placement: claim rank via LDS atomic, write node-sorted record
    uint2* o = srt + (size_t)b * CAP;
    for (int k = tid; k < n; k += 256) {
        uint2 v = r[k];
        int local = (int)(v.x >> 17);
        int p = atomicAdd(&offs[local], 1);
        o[p] = v;
    }
}

// ---------------- K3: atomic-free gather + fused GRU/attention/output ----------------
// 32 lanes per node; node's records are contiguous -> coalesced reads
__global__ __launch_bounds__(256) void gather2_k(const uint2* __restrict__ srt,
                                                 const float* __restrict__ dinv,
                                                 const int* __restrict__ starts,
                                                 const int* __restrict__ cnts,
                                                 const float* __restrict__ x,
                                                 const float* __restrict__ tabs,
                                                 const float* __restrict__ w_out,
                                                 const float* __restrict__ b_out,
                                                 float* __restrict__ out) {
    int t = blockIdx.x * blockDim.x + threadIdx.x;
    int i = t >> 5;
    int j = t & 31;

    int start = starts[i];
    int n     = cnts[i];

    float acc[PP];
    #pragma unroll
    for (int p = 0; p < PP; ++p) acc[p] = 0.f;

    for (int k = j; k < n; k += 32) {
        uint2 v = srt[start + k];
        int   s = (int)(v.x & 0x1FFFFu);
        float c = __uint_as_float(v.y) * dinv[s];
        const float4* xs = (const float4*)(x + (size_t)s * PP);
        float4 v0 = xs[0], v1 = xs[1], v2 = xs[2];
        acc[0] += c * v0.x;  acc[1] += c * v0.y;  acc[2]  += c * v0.z;  acc[3]  += c * v0.w;
        acc[4] += c * v1.x;  acc[5] += c * v1.y;  acc[6]  += c * v1.z;  acc[7]  += c * v1.w;
        acc[8] += c * v2.x;  acc[9] += c * v2.y;  acc[10] += c * v2.z;  acc[11] += c * v2.w;
    }

    // butterfly: all 32 lanes end with the full 12-vector sum
    #pragma unroll
    for (int p = 0; p < PP; ++p) {
        #pragma unroll
        for (int off = 16; off > 0; off >>= 1)
            acc[p] += __shfl_xor(acc[p], off, 32);
    }

    float dv  = dinv[i];
    float dv2 = dv * dv;

    float azj = tabs[16 + j];
    float czj = tabs[16 + FF + j];
    float ahj = tabs[16 + 2 * FF + j];
    float chj = tabs[16 + 3 * FF + j];

    float accum = 0.f;
    #pragma unroll
    for (int p = 0; p < PP; ++p) {
        float sp = dv * acc[p] + dv2 * x[(size_t)i * PP + p];
        float pr = tabs[p];
        float uz = sp * azj + czj;
        float uh = sp * ahj + chj;
        float one_minus_z = 1.0f / (1.0f + __expf(uz));   // sigma(-uz)
        float e2h = __expf(2.0f * uh);
        float th  = 1.0f - 2.0f / (e2h + 1.0f);           // tanh(uh)
        accum += pr * one_minus_z * th;
    }
    float h = fmaxf(accum, 0.f) * w_out[j];
    #pragma unroll
    for (int off = 16; off > 0; off >>= 1)
        h += __shfl_xor(h, off, 32);
    if (j == 0) out[i] = h + b_out[0];
}

// ---------------- fallback path (round-2 proven kernels) ----------------
__global__ __launch_bounds__(256) void deg_k(const int* __restrict__ dst,
                                             const float* __restrict__ ew,
                                             float* __restrict__ deg) {
    int stride = gridDim.x * blockDim.x;
    for (int e = blockIdx.x * blockDim.x + threadIdx.x; e < EE; e += stride)
        atomicAdd(&deg[dst[e]], ew[e]);
}

__global__ __launch_bounds__(256) void dinv_self_k(const float* __restrict__ x,
                                                   float* __restrict__ deg,
                                                   float* __restrict__ agg) {
    int i = blockIdx.x * blockDim.x + threadIdx.x;
    if (i >= NN) return;
    float d  = deg[i] + 1.0f;
    float dv = rsqrtf(d);
    deg[i]   = dv;
    float dv2 = dv * dv;
    const float4* xr = (const float4*)(x + (size_t)i * PP);
    float4* ar = (float4*)(agg + (size_t)i * PP);
    #pragma unroll
    for (int q = 0; q < 3; ++q) {
        float4 v = xr[q];
        v.x *= dv2; v.y *= dv2; v.z *= dv2; v.w *= dv2;
        ar[q] = v;
    }
}

__global__ __launch_bounds__(256) void agg_k(const int* __restrict__ src,
                                             const int* __restrict__ dst,
                                             const float* __restrict__ ew,
                                             const float* __restrict__ x,
                                             const float* __restrict__ dinv,
                                             float* __restrict__ agg) {
    int stride = gridDim.x * blockDim.x;
    for (int e = blockIdx.x * blockDim.x + threadIdx.x; e < EE; e += stride) {
        int s = src[e];
        int d = dst[e];
        float nw = dinv[s] * ew[e] * dinv[d];
        const float4* xs = (const float4*)(x + (size_t)s * PP);
        float* ad = agg + (size_t)d * PP;
        float4 v0 = xs[0], v1 = xs[1], v2 = xs[2];
        atomicAdd(&ad[0],  nw * v0.x);
        atomicAdd(&ad[1],  nw * v0.y);
        atomicAdd(&ad[2],  nw * v0.z);
        atomicAdd(&ad[3],  nw * v0.w);
        atomicAdd(&ad[4],  nw * v1.x);
        atomicAdd(&ad[5],  nw * v1.y);
        atomicAdd(&ad[6],  nw * v1.z);
        atomicAdd(&ad[7],  nw * v1.w);
        atomicAdd(&ad[8],  nw * v2.x);
        atomicAdd(&ad[9],  nw * v2.y);
        atomicAdd(&ad[10], nw * v2.z);
        atomicAdd(&ad[11], nw * v2.w);
    }
}

__global__ __launch_bounds__(256) void node_k(const float* __restrict__ agg,
                                              const float* __restrict__ tabs,
                                              const float* __restrict__ w_out,
                                              const float* __restrict__ b_out,
                                              float* __restrict__ out) {
    int t = blockIdx.x * blockDim.x + threadIdx.x;
    int i = t >> 5;
    int j = t & 31;
    if (i >= NN) return;
    float azj = tabs[16 + j];
    float czj = tabs[16 + FF + j];
    float ahj = tabs[16 + 2 * FF + j];
    float chj = tabs[16 + 3 * FF + j];
    float acc = 0.f;
    #pragma unroll
    for (int p = 0; p < PP; ++p) {
        float s  = agg[i * PP + p];
        float pr = tabs[p];
        float uz = s * azj + czj;
        float uh = s * ahj + chj;
        float one_minus_z = 1.0f / (1.0f + __expf(uz));
        float e2h = __expf(2.0f * uh);
        float th  = 1.0f - 2.0f / (e2h + 1.0f);
        acc += pr * one_minus_z * th;
    }
    float h = fmaxf(acc, 0.f) * w_out[j];
    #pragma unroll
    for (int off = 16; off > 0; off >>= 1)
        h += __shfl_xor(h, off, 32);
    if (j == 0) out[i] = h + b_out[0];
}

extern "C" void kernel_launch(void* const* d_in, const int* in_sizes, int n_in,
                              void* d_out, int out_size, void* d_ws, size_t ws_size,
                              hipStream_t stream) {
    const float* x    = (const float*)d_in[0];
    const int*   ei   = (const int*)d_in[1];
    const float* ew   = (const float*)d_in[2];
    const float* att  = (const float*)d_in[3];
    const float* wc_z = (const float*)d_in[4];
    const float* bc_z = (const float*)d_in[5];
    const float* wc_h = (const float*)d_in[8];
    const float* bc_h = (const float*)d_in[9];
    const float* wl_z = (const float*)d_in[10];
    const float* bl_z = (const float*)d_in[11];
    const float* wl_h = (const float*)d_in[14];
    const float* bl_h = (const float*)d_in[15];
    const float* wout = (const float*)d_in[16];
    const float* bout = (const float*)d_in[17];
    float* out = (float*)d_out;

    const int* src = ei;
    const int* dst = ei + EE;

    size_t region = (size_t)BB * CAP * sizeof(uint2);   // 53.65 MB
    size_t need = 2 * region + BB * 4 + (size_t)NN * 12 + 1024;

    if (ws_size >= need) {
        uint2* recs       = (uint2*)d_ws;
        uint2* srt        = (uint2*)((char*)d_ws + region);
        int*   bucket_cnt = (int*)((char*)d_ws + 2 * region);
        float* dinv       = (float*)(bucket_cnt + BB + 1);   // +1 keeps 8B align slack
        int*   starts     = (int*)(dinv + NN);
        int*   cnts       = starts + NN;
        float* tabs       = (float*)(cnts + NN);

        hipMemsetAsync(bucket_cnt, 0, BB * sizeof(int), stream);
        precompute_k<<<1, 64, 0, stream>>>(att, wc_z, bc_z, wc_h, bc_h, wl_z, bl_z, wl_h, bl_h, tabs);
        bucket_k<<<K1B, 256, 0, stream>>>(src, dst, ew, bucket_cnt, recs);
        sort_k<<<BB, 256, 0, stream>>>(bucket_cnt, recs, srt, dinv, starts, cnts);
        gather2_k<<<NN * 32 / 256, 256, 0, stream>>>(srt, dinv, starts, cnts, x, tabs, wout, bout, out);
    } else {
        float* deg  = (float*)d_ws;
        float* agg  = deg + NN;
        float* tabs = agg + (size_t)NN * PP;

        hipMemsetAsync(deg, 0, NN * sizeof(float), stream);
        precompute_k<<<1, 64, 0, stream>>>(att, wc_z, bc_z, wc_h, bc_h, wl_z, bl_z, wl_h, bl_h, tabs);
        deg_k<<<4096, 256, 0, stream>>>(dst, ew, deg);
        dinv_self_k<<<(NN + 255) / 256, 256, 0, stream>>>(x, deg, agg);
        agg_k<<<8192, 256, 0, stream>>>(src, dst, ew, x, deg, agg);
        node_k<<<NN * 32 / 256, 256, 0, stream>>>(agg, tabs, wout, bout, out);
    }
}